// Round 3
// baseline (123.090 us; speedup 1.0000x reference)
//
#include <hip/hip_runtime.h>
#include <hip/hip_bf16.h>

// D = 16 (in == out features), N = 50000 nodes, E = 800000 edges.
//
// Algebraic refactor of the reference:
//   messages[e,w] = sum_{u,v} x[row_e,u] * x[col_e,v] * W_tp[u,v,w]
//   out0[n,w]     = sum_{e: row_e=n} messages[e,w]
//                 = sum_{u,v} x[n,u] * W_tp[u,v,w] * agg[n,v]
//   with agg[n,v] = sum_{e: row_e=n} x[col_e,v]          (scatter-add of raw features)
//   final[n,o]    = sum_w out0[n,w]*weight[o,w] + bias[o]
//                 = sum_{u,v} x[n,u]*agg[n,v]*Wf[u,v,o] + bias[o]
//   with Wf[u,v,o] = sum_w W_tp[u,v,w]*weight[o,w]       (fused on device, 4096 elems)
//
// This turns 800k per-edge bilinears (7 GFLOP) into 12.8M scalar atomics +
// 50k per-node bilinears (0.4 GFLOP).

#define D16 16
#define WF_STRIDE 260  // padded row stride for Wf[o][u*16+v]; 260*4B = 1040B, 16B-aligned

// ---- build fused weight: Wf_t[o*260 + u*16 + v] = sum_w W_tp[(u*16+v)*16+w] * weight[o*16+w]
__global__ __launch_bounds__(256) void fuse_w(const float* __restrict__ Wtp,
                                              const float* __restrict__ wgt,
                                              float* __restrict__ Wf) {
    int t  = blockIdx.x * 256 + threadIdx.x;   // 4096 threads total
    int o  = t & 15;
    int uv = t >> 4;                           // [0,256)
    float acc = 0.f;
#pragma unroll
    for (int w = 0; w < D16; ++w)
        acc = fmaf(Wtp[uv * D16 + w], wgt[o * D16 + w], acc);
    Wf[o * WF_STRIDE + uv] = acc;
}

// ---- scatter: agg[row_e][v] += x[col_e][v], one thread per (edge, v)
__global__ __launch_bounds__(256) void scatter_k(const int* __restrict__ ei,
                                                 const float* __restrict__ x,
                                                 float* __restrict__ agg,
                                                 int E) {
    int t = blockIdx.x * 256 + threadIdx.x;
    if (t >= E * D16) return;
    int e = t >> 4;
    int v = t & 15;
    int r = ei[e];        // row
    int c = ei[E + e];    // col
    unsafeAtomicAdd(&agg[r * D16 + v], x[c * D16 + v]);
}

// ---- per-node bilinear + fused linear: out[n,o] = bias[o] + sum_{u,v} x[n,u]*agg[n,v]*Wf[o][u*16+v]
__global__ __launch_bounds__(256) void bilinear_k(const float* __restrict__ x,
                                                  const float* __restrict__ agg,
                                                  const float* __restrict__ Wf,
                                                  const float* __restrict__ bias,
                                                  float* __restrict__ out,
                                                  int N) {
    __shared__ float sWf[D16 * WF_STRIDE];  // 16.6 KB
    __shared__ float sx[256];
    __shared__ float sa[256];
    __shared__ float sbias[D16];

    int t = threadIdx.x;
    for (int i = t; i < D16 * WF_STRIDE; i += 256) sWf[i] = Wf[i];
    int gbase = blockIdx.x * 256;           // block covers 16 nodes (256 feature elems)
    int g = gbase + t;
    int total = N * D16;
    if (g < total) { sx[t] = x[g]; sa[t] = agg[g]; }
    if (t < D16) sbias[t] = bias[t];
    __syncthreads();

    if (g >= total) return;
    int nl = t >> 4;      // local node
    int o  = t & 15;      // output feature

    float xv[D16], av[D16];
#pragma unroll
    for (int i = 0; i < D16; ++i) {
        xv[i] = sx[nl * D16 + i];
        av[i] = sa[nl * D16 + i];
    }

    const float* wrow = &sWf[o * WF_STRIDE];
    float acc = sbias[o];
#pragma unroll
    for (int u = 0; u < D16; ++u) {
        float tu = 0.f;
#pragma unroll
        for (int v = 0; v < D16; ++v)          // consecutive v -> ds_read_b128-friendly
            tu = fmaf(av[v], wrow[u * D16 + v], tu);
        acc = fmaf(xv[u], tu, acc);
    }
    out[g] = acc;
}

extern "C" void kernel_launch(void* const* d_in, const int* in_sizes, int n_in,
                              void* d_out, int out_size, void* d_ws, size_t ws_size,
                              hipStream_t stream) {
    const float* x    = (const float*)d_in[0];
    const int*   ei   = (const int*)d_in[1];
    const float* Wtp  = (const float*)d_in[2];
    const float* wgt  = (const float*)d_in[3];
    const float* bias = (const float*)d_in[4];
    float* out = (float*)d_out;

    int N = in_sizes[0] / D16;   // 50000
    int E = in_sizes[1] / 2;     // 800000

    float* agg = (float*)d_ws;                   // N*16 floats
    float* Wf  = agg + (size_t)N * D16;          // 16*260 floats

    // ws is poisoned 0xAA before every launch -> zero the accumulator
    hipMemsetAsync(agg, 0, (size_t)N * D16 * sizeof(float), stream);

    fuse_w<<<16, 256, 0, stream>>>(Wtp, wgt, Wf);

    int sthreads = E * D16;                      // 12.8M
    scatter_k<<<(sthreads + 255) / 256, 256, 0, stream>>>(ei, x, agg, E);

    bilinear_k<<<(N * D16 + 255) / 256, 256, 0, stream>>>(x, agg, Wf, bias, out, N);
}